// Round 1
// baseline (529.242 us; speedup 1.0000x reference)
//
#include <hip/hip_runtime.h>

#define HW 4096
#define DECAYF 0.99f
#define ONEMF 0.01f
#define EPSF 1e-5f

// ws float layout:
// [0, 65536)      dw accumulator (K*D)
// [65536, 66560)  counts (K)
// [66560, 67584)  c_half = 0.5*||e_k||^2 (K)
// [67584]         sse accumulator (loss)

__device__ __forceinline__ float wave_reduce_add(float v) {
#pragma unroll
    for (int o = 32; o > 0; o >>= 1) v += __shfl_xor(v, o, 64);
    return v;
}

// Zero dw/counts/sse and compute c_half. grid 256 x 256.
__global__ __launch_bounds__(256) void prep_kernel(const float* __restrict__ E,
                                                   float* __restrict__ ws) {
    const int bid = blockIdx.x, tid = threadIdx.x;
    ws[bid * 256 + tid] = 0.0f;                        // dw
    if (bid < 4) ws[65536 + bid * 256 + tid] = 0.0f;   // counts
    if (bid == 4 && tid == 0) ws[67584] = 0.0f;        // sse
    const int w = tid >> 6, lane = tid & 63;
    const int k = bid * 4 + w;                         // 256*4 = 1024 codes
    const float v = E[k * 64 + lane];
    const float s = wave_reduce_add(v * v);
    if (lane == 0) ws[66560 + k] = 0.5f * s;
}

// Main: argmin + q_st + one-hot + dw/count scatter + sse. grid 1024 x 256.
__global__ __launch_bounds__(256) void vq_main(const float* __restrict__ x,
                                               const float* __restrict__ E,
                                               const float* __restrict__ chalf,
                                               float* __restrict__ out,
                                               float* __restrict__ ws) {
    const int tid = threadIdx.x;
    const int lane = tid & 63;
    const int w = __builtin_amdgcn_readfirstlane(tid >> 6);
    const int blk = blockIdx.x;
    const int b = blk >> 6;            // batch index
    const int hw0 = (blk & 63) << 6;   // hw offset of this block's 64 tokens
    const int tok0 = blk << 6;         // global token index base

    __shared__ float xs[64 * 65];      // x tile [token][dim], pad 65 (2-way banks: free)
    __shared__ float r_s[8][64];
    __shared__ int r_i[8][64];
    __shared__ int idx_sh[64];

    // Each lane = one token; load its 64 dims (coalesced across lanes per c).
    float xr[64];
    const float* xb = x + (size_t)(b * 64) * HW + hw0 + lane;
#pragma unroll
    for (int c = 0; c < 64; ++c) xr[c] = xb[(size_t)c * HW];
    if (w == 0) {
#pragma unroll
        for (int c = 0; c < 64; ++c) xs[lane * 65 + c] = xr[c];
    }
    __syncthreads();

    // Each wave scans its 256-code quarter; track top-2 scores s = x·e - 0.5||e||^2.
    float b1 = -1e30f, b2 = -1e30f;
    int i1 = 0, i2 = 1;
    const int kbase = w << 8;
    for (int kk = 0; kk < 256; ++kk) {
        const int k = kbase + kk;               // wave-uniform
        const float* er = E + k * 64;
        float a0 = 0.f, a1 = 0.f, a2 = 0.f, a3 = 0.f;
#pragma unroll
        for (int j = 0; j < 16; ++j) {
            a0 = fmaf(er[4 * j + 0], xr[4 * j + 0], a0);
            a1 = fmaf(er[4 * j + 1], xr[4 * j + 1], a1);
            a2 = fmaf(er[4 * j + 2], xr[4 * j + 2], a2);
            a3 = fmaf(er[4 * j + 3], xr[4 * j + 3], a3);
        }
        const float s = (a0 + a1) + (a2 + a3) - chalf[k];
        if (s > b1) { b2 = b1; i2 = i1; b1 = s; i1 = k; }
        else if (s > b2) { b2 = s; i2 = k; }
    }
    r_s[w * 2 + 0][lane] = b1; r_i[w * 2 + 0][lane] = i1;
    r_s[w * 2 + 1][lane] = b2; r_i[w * 2 + 1][lane] = i2;
    __syncthreads();

    if (tid < 64) {  // wave 0: merge 8 candidates, fp64 re-rank of top-2
        float B1 = -1e30f, B2 = -1e30f; int I1 = 0, I2 = 1;
#pragma unroll
        for (int c8 = 0; c8 < 8; ++c8) {
            const float s = r_s[c8][tid]; const int ii = r_i[c8][tid];
            if (s > B1) { B2 = B1; I2 = I1; B1 = s; I1 = ii; }
            else if (s > B2) { B2 = s; I2 = ii; }
        }
        const int ca = I1 < I2 ? I1 : I2;
        const int cb = I1 < I2 ? I2 : I1;
        const float* Ea = E + ca * 64;
        const float* Eb = E + cb * 64;
        double sa = 0, ea = 0, sb = 0, eb = 0, x2 = 0;
#pragma unroll 8
        for (int c = 0; c < 64; ++c) {
            const double xv = (double)xs[tid * 65 + c];
            const double va = (double)Ea[c], vb = (double)Eb[c];
            sa += xv * va; ea += va * va;
            sb += xv * vb; eb += vb * vb;
            x2 += xv * xv;
        }
        const double qa = ea - 2.0 * sa;
        const double qb = eb - 2.0 * sb;
        int best; double q;
        if (qb < qa) { best = cb; q = qb; } else { best = ca; q = qa; }
        idx_sh[tid] = best;
        float d = (float)(q + x2);          // ||x - e||^2, fp64-accurate
        if (d < 0.f) d = 0.f;
        const float ssum = wave_reduce_add(d);
        if (tid == 0) atomicAdd(&ws[67584], ssum);
        atomicAdd(&ws[65536 + best], 1.0f); // counts
    }
    __syncthreads();

    // q_st output (numerically x + (e - x)): lanes = tokens, wave w covers 16 dims.
    float* outq = out + 1;
    {
        const int kb = idx_sh[lane];
#pragma unroll
        for (int cc = 0; cc < 16; ++cc) {
            const int c = (w << 4) + cc;
            const float eq = E[kb * 64 + c];          // gather, L2-hot
            const float xv = xs[lane * 65 + c];
            outq[(size_t)(b * 64 + c) * HW + hw0 + lane] = xv + (eq - xv);
        }
    }
    // dw scatter-add: lane = dim (coalesced atomics), wave w covers 16 tokens.
    {
#pragma unroll
        for (int tt = 0; tt < 16; ++tt) {
            const int t = (w << 4) + tt;
            const int kb = idx_sh[t];                 // wave-uniform
            atomicAdd(&ws[kb * 64 + lane], xs[t * 65 + lane]);
        }
    }
    // one-hot encodings: per iteration the block writes one full 1024-col row.
    float* enc = out + 1 + (size_t)4194304;
    {
        const int c0 = tid * 4;
        for (int it = 0; it < 64; ++it) {
            const int kb = idx_sh[it];
            float* p = enc + (size_t)(tok0 + it) * 1024 + c0;
            __builtin_nontemporal_store(c0 + 0 == kb ? 1.0f : 0.0f, p + 0);
            __builtin_nontemporal_store(c0 + 1 == kb ? 1.0f : 0.0f, p + 1);
            __builtin_nontemporal_store(c0 + 2 == kb ? 1.0f : 0.0f, p + 2);
            __builtin_nontemporal_store(c0 + 3 == kb ? 1.0f : 0.0f, p + 3);
        }
    }
}

// new_cs (Laplace-smoothed) + loss. 1 block x 1024.
__global__ __launch_bounds__(1024) void fin_cs(const float* __restrict__ cs_in,
                                               float* __restrict__ out,
                                               const float* __restrict__ ws) {
    __shared__ float red[16];
    __shared__ float n_sh;
    const int tid = threadIdx.x;
    const float raw = cs_in[tid] * DECAYF + ONEMF * ws[65536 + tid];
    const float s = wave_reduce_add(raw);
    if ((tid & 63) == 0) red[tid >> 6] = s;
    __syncthreads();
    if (tid == 0) {
        float n = 0.f;
#pragma unroll
        for (int i = 0; i < 16; ++i) n += red[i];
        n_sh = n;
        out[0] = 0.25f * ws[67584] * (1.0f / 4194304.0f);  // loss
    }
    __syncthreads();
    const float n = n_sh;
    out[71368705 + tid] = (raw + EPSF) / (n + 1024.0f * EPSF) * n;
}

// new_ema_weight and new_embedding. grid 256 x 256.
__global__ __launch_bounds__(256) void fin_w(const float* __restrict__ emaw,
                                             float* __restrict__ out,
                                             const float* __restrict__ ws) {
    const int i = blockIdx.x * 256 + threadIdx.x;
    const float val = emaw[i] * DECAYF + ONEMF * ws[i];
    out[71369729 + i] = val;                               // new_ema_weight
    const float cs = out[71368705 + (i >> 6)];             // new_cs (written by fin_cs)
    out[71303169 + i] = val / cs;                          // new_embedding
}

extern "C" void kernel_launch(void* const* d_in, const int* in_sizes, int n_in,
                              void* d_out, int out_size, void* d_ws, size_t ws_size,
                              hipStream_t stream) {
    const float* x    = (const float*)d_in[0];   // [16,64,64,64]
    const float* E    = (const float*)d_in[1];   // [1024,64]
    const float* cs   = (const float*)d_in[2];   // [1024]
    const float* emaw = (const float*)d_in[3];   // [1024,64]
    float* out = (float*)d_out;
    float* ws  = (float*)d_ws;

    prep_kernel<<<256, 256, 0, stream>>>(E, ws);
    vq_main<<<1024, 256, 0, stream>>>(x, E, ws + 66560, out, ws);
    fin_cs<<<1, 1024, 0, stream>>>(cs, out, ws);
    fin_w<<<256, 256, 0, stream>>>(emaw, out, ws);
}

// Round 3
// 415.738 us; speedup vs baseline: 1.2730x; 1.2730x over previous
//
#include <hip/hip_runtime.h>

#define HW 4096
#define DECAYF 0.99f
#define ONEMF 0.01f
#define EPSF 1e-5f

typedef __bf16 bf16x8 __attribute__((ext_vector_type(8)));
typedef float f32x4 __attribute__((ext_vector_type(4)));
typedef unsigned short ushort8 __attribute__((ext_vector_type(8)));

// ws layout (float indices):
// [0,65536)        dw accumulator (K*D)
// [65536,66560)    counts (K)
// [66560,67584)    nchalf = -0.5*||e_k||^2
// [67584]          sse
// [67600,100368)   E_hi as bf16 (ushort), row-major [K][D]
// [100368,133136)  E_lo as bf16 (ushort)
#define WS_COUNTS 65536
#define WS_NCHALF 66560
#define WS_SSE    67584
#define WS_EHI    67600
#define WS_ELO    100368

__device__ __forceinline__ float wave_reduce_add(float v) {
#pragma unroll
    for (int o = 32; o > 0; o >>= 1) v += __shfl_xor(v, o, 64);
    return v;
}

__device__ __forceinline__ unsigned short bf_rne(float f) {
    unsigned int u = __float_as_uint(f);
    unsigned int r = u + 0x7fffu + ((u >> 16) & 1u);
    return (unsigned short)(r >> 16);
}

// Zero dw/counts/sse; split E into bf16 hi/lo; nchalf. grid 256 x 256.
__global__ __launch_bounds__(256) void prep_kernel(const float* __restrict__ E,
                                                   float* __restrict__ ws) {
    const int bid = blockIdx.x, tid = threadIdx.x;
    const int id = bid * 256 + tid;            // element of E (k = id>>6, c = id&63)
    ws[id] = 0.0f;                             // dw
    if (bid < 4) ws[WS_COUNTS + bid * 256 + tid] = 0.0f;
    if (bid == 4 && tid == 0) ws[WS_SSE] = 0.0f;
    const float v = E[id];
    const unsigned short h = bf_rne(v);
    const float hf = __uint_as_float((unsigned int)h << 16);
    const unsigned short l = bf_rne(v - hf);
    ((unsigned short*)(ws + WS_EHI))[id] = h;
    ((unsigned short*)(ws + WS_ELO))[id] = l;
    const int lane = tid & 63;
    const float s = wave_reduce_add(v * v);
    if (lane == 0) ws[WS_NCHALF + (id >> 6)] = -0.5f * s;
}

// Main: MFMA scores + top-2 + fp64 re-rank + all scatter outputs.
// grid 512 x 256; each block = 128 tokens.
__global__ __launch_bounds__(256) void vq_main(const float* __restrict__ x,
                                               const float* __restrict__ E,
                                               float* __restrict__ out,
                                               float* __restrict__ ws) {
    const int tid = threadIdx.x;
    const int lane = tid & 63;
    const int w = tid >> 6;
    const int blk = blockIdx.x;
    const int b = blk >> 5;            // batch
    const int hw0 = (blk & 31) << 7;   // hw offset (128 tokens)
    const int tok0 = blk << 7;

    __shared__ float xs[128 * 68];     // [token][dim], stride 68 keeps rows 16B-aligned
    __shared__ int i1sh[128], i2sh[128], idx_sh[128];

    // Stage x tile (fully coalesced: consecutive tid -> consecutive hw).
    {
        const float* xb = x + ((size_t)b << 18) + hw0;
#pragma unroll
        for (int cc = 0; cc < 32; ++cc) {
            const int id = cc * 256 + tid;
            const int c = id >> 7, t = id & 127;
            xs[t * 68 + c] = xb[((size_t)c << 12) + t];
        }
    }
    __syncthreads();

    const int q = lane >> 4, m = lane & 15;

    // A fragments: 2 row-tiles (16 tokens each) x 2 K-slices x (hi,lo).
    bf16x8 Ah[2][2], Al[2][2];
#pragma unroll
    for (int t = 0; t < 2; ++t) {
        const int tok = w * 32 + t * 16 + m;
#pragma unroll
        for (int s = 0; s < 2; ++s) {
            const float* p = &xs[tok * 68 + s * 32 + q * 8];
            ushort8 hu, lu;
#pragma unroll
            for (int j = 0; j < 8; ++j) {
                const float f = p[j];
                const unsigned short h = bf_rne(f);
                const float hf = __uint_as_float((unsigned int)h << 16);
                hu[j] = h;
                lu[j] = bf_rne(f - hf);
            }
            Ah[t][s] = __builtin_bit_cast(bf16x8, hu);
            Al[t][s] = __builtin_bit_cast(bf16x8, lu);
        }
    }

    const ushort8* __restrict__ Ehp = (const ushort8*)(ws + WS_EHI);  // [K][8] groups of 8 dims
    const ushort8* __restrict__ Elp = (const ushort8*)(ws + WS_ELO);
    const float* __restrict__ ncp = ws + WS_NCHALF;

    // Per-lane running top-2 per C/D row (4 regs x 2 tiles).
    float b1[2][4], b2[2][4];
    int i1[2][4], i2[2][4];
#pragma unroll
    for (int t = 0; t < 2; ++t)
#pragma unroll
        for (int r = 0; r < 4; ++r) { b1[t][r] = -1e30f; b2[t][r] = -1e30f; i1[t][r] = 0; i2[t][r] = 1; }

    // Register double-buffered B fragments; this lane's col = m.
    ushort8 nb0h = Ehp[m * 8 + q];
    ushort8 nb1h = Ehp[m * 8 + 4 + q];
    ushort8 nb0l = Elp[m * 8 + q];
    ushort8 nb1l = Elp[m * 8 + 4 + q];
    float nnc = ncp[m];

    for (int ck = 0; ck < 64; ++ck) {
        const ushort8 c0h = nb0h, c1h = nb1h, c0l = nb0l, c1l = nb1l;
        const float nc = nnc;
        if (ck < 63) {
            const int code = (ck + 1) * 16 + m;
            nb0h = Ehp[code * 8 + q];
            nb1h = Ehp[code * 8 + 4 + q];
            nb0l = Elp[code * 8 + q];
            nb1l = Elp[code * 8 + 4 + q];
            nnc = ncp[code];
        }
        const bf16x8 bh0 = __builtin_bit_cast(bf16x8, c0h);
        const bf16x8 bh1 = __builtin_bit_cast(bf16x8, c1h);
        const bf16x8 bl0 = __builtin_bit_cast(bf16x8, c0l);
        const bf16x8 bl1 = __builtin_bit_cast(bf16x8, c1l);
        const int idx = ck * 16 + m;
#pragma unroll
        for (int t = 0; t < 2; ++t) {
            f32x4 acc = {nc, nc, nc, nc};   // score = x.e - 0.5||e||^2
            acc = __builtin_amdgcn_mfma_f32_16x16x32_bf16(Ah[t][0], bh0, acc, 0, 0, 0);
            acc = __builtin_amdgcn_mfma_f32_16x16x32_bf16(Ah[t][1], bh1, acc, 0, 0, 0);
            acc = __builtin_amdgcn_mfma_f32_16x16x32_bf16(Al[t][0], bh0, acc, 0, 0, 0);
            acc = __builtin_amdgcn_mfma_f32_16x16x32_bf16(Al[t][1], bh1, acc, 0, 0, 0);
            acc = __builtin_amdgcn_mfma_f32_16x16x32_bf16(Ah[t][0], bl0, acc, 0, 0, 0);
            acc = __builtin_amdgcn_mfma_f32_16x16x32_bf16(Ah[t][1], bl1, acc, 0, 0, 0);
#pragma unroll
            for (int r = 0; r < 4; ++r) {
                const float s = acc[r];
                const bool cA = s > b1[t][r];
                const bool cB = s > b2[t][r];
                b2[t][r] = cA ? b1[t][r] : (cB ? s : b2[t][r]);
                i2[t][r] = cA ? i1[t][r] : (cB ? idx : i2[t][r]);
                b1[t][r] = cA ? s : b1[t][r];
                i1[t][r] = cA ? idx : i1[t][r];
            }
        }
    }

    // Merge top-2 across the 16 lanes of each quad-group (cols of the row).
#pragma unroll
    for (int d = 1; d < 16; d <<= 1) {
#pragma unroll
        for (int t = 0; t < 2; ++t)
#pragma unroll
            for (int r = 0; r < 4; ++r) {
                const float ob1 = __shfl_xor(b1[t][r], d, 64);
                const int   oi1 = __shfl_xor(i1[t][r], d, 64);
                const float ob2 = __shfl_xor(b2[t][r], d, 64);
                const int   oi2 = __shfl_xor(i2[t][r], d, 64);
                const bool wv = ob1 > b1[t][r];
                const float t1 = wv ? ob1 : b1[t][r]; const int ti1 = wv ? oi1 : i1[t][r];
                const float sA = wv ? b1[t][r] : ob1; const int siA = wv ? i1[t][r] : oi1;
                const float sB = wv ? ob2 : b2[t][r]; const int siB = wv ? oi2 : i2[t][r];
                const bool w2 = sB > sA;
                b1[t][r] = t1; i1[t][r] = ti1;
                b2[t][r] = w2 ? sB : sA; i2[t][r] = w2 ? siB : siA;
            }
    }
    if (m == 0) {   // quad leaders publish rows 4q+r of each tile
#pragma unroll
        for (int t = 0; t < 2; ++t)
#pragma unroll
            for (int r = 0; r < 4; ++r) {
                const int tokL = w * 32 + t * 16 + q * 4 + r;
                i1sh[tokL] = i1[t][r];
                i2sh[tokL] = i2[t][r];
            }
    }

    // fp64 re-rank of the two candidates (same wave -> no barrier needed).
    float dval = 0.0f;
    if (lane < 32) {
        const int tokL = w * 32 + lane;
        const int I1 = i1sh[tokL], I2 = i2sh[tokL];
        const int ca = I1 < I2 ? I1 : I2;
        const int cb = I1 < I2 ? I2 : I1;
        const float* Ea = E + ca * 64;
        const float* Eb = E + cb * 64;
        const float* xr = &xs[tokL * 68];
        double sa = 0, ea = 0, sb = 0, eb = 0, x2 = 0;
#pragma unroll 8
        for (int c = 0; c < 64; ++c) {
            const double xv = (double)xr[c];
            const double va = (double)Ea[c], vb = (double)Eb[c];
            sa += xv * va; ea += va * va;
            sb += xv * vb; eb += vb * vb;
            x2 += xv * xv;
        }
        const double qa = ea - 2.0 * sa;
        const double qb = eb - 2.0 * sb;
        int best; double qq;
        if (qb < qa) { best = cb; qq = qb; } else { best = ca; qq = qa; }
        idx_sh[tokL] = best;
        float dd = (float)(qq + x2);
        dval = dd < 0.f ? 0.f : dd;
        atomicAdd(&ws[WS_COUNTS + best], 1.0f);
    }
    const float ssum = wave_reduce_add(dval);
    if (lane == 0) atomicAdd(&ws[WS_SSE], ssum);
    __syncthreads();

    // q_st output (reference order: x + (e - x)).
    float* outq = out + 1;
#pragma unroll
    for (int cc = 0; cc < 32; ++cc) {
        const int id = cc * 256 + tid;
        const int c = id >> 7, t = id & 127;
        const int kb = idx_sh[t];
        const float xv = xs[t * 68 + c];
        const float eq = E[kb * 64 + c];
        outq[((size_t)(b * 64 + c) << 12) + hw0 + t] = xv + (eq - xv);
    }
    // dw scatter-add: lane = dim (coalesced atomics), wave-uniform row.
#pragma unroll 4
    for (int tt = 0; tt < 32; ++tt) {
        const int t = w * 32 + tt;
        const int kb = idx_sh[t];
        atomicAdd(&ws[kb * 64 + lane], xs[t * 68 + lane]);
    }
    // one-hot encodings: one f32x4 nontemporal store per thread per row.
    {
        float* enc = out + 1 + (size_t)4194304;
        const int c0 = tid << 2;
        for (int t = 0; t < 128; ++t) {
            const int kb = idx_sh[t];
            f32x4 v;
            v[0] = (c0 == kb) ? 1.0f : 0.0f;
            v[1] = (c0 + 1 == kb) ? 1.0f : 0.0f;
            v[2] = (c0 + 2 == kb) ? 1.0f : 0.0f;
            v[3] = (c0 + 3 == kb) ? 1.0f : 0.0f;
            __builtin_nontemporal_store(v, (f32x4*)(enc + (size_t)(tok0 + t) * 1024 + c0));
        }
    }
}

// new_cs (Laplace-smoothed) + loss. 1 block x 1024.
__global__ __launch_bounds__(1024) void fin_cs(const float* __restrict__ cs_in,
                                               float* __restrict__ out,
                                               const float* __restrict__ ws) {
    __shared__ float red[16];
    __shared__ float n_sh;
    const int tid = threadIdx.x;
    const float raw = cs_in[tid] * DECAYF + ONEMF * ws[WS_COUNTS + tid];
    const float s = wave_reduce_add(raw);
    if ((tid & 63) == 0) red[tid >> 6] = s;
    __syncthreads();
    if (tid == 0) {
        float n = 0.f;
#pragma unroll
        for (int i = 0; i < 16; ++i) n += red[i];
        n_sh = n;
        out[0] = 0.25f * ws[WS_SSE] * (1.0f / 4194304.0f);  // loss
    }
    __syncthreads();
    const float n = n_sh;
    out[71368705 + tid] = (raw + EPSF) / (n + 1024.0f * EPSF) * n;
}

// new_ema_weight and new_embedding. grid 256 x 256.
__global__ __launch_bounds__(256) void fin_w(const float* __restrict__ emaw,
                                             float* __restrict__ out,
                                             const float* __restrict__ ws) {
    const int i = blockIdx.x * 256 + threadIdx.x;
    const float val = emaw[i] * DECAYF + ONEMF * ws[i];
    out[71369729 + i] = val;                               // new_ema_weight
    const float cs = out[71368705 + (i >> 6)];             // new_cs (from fin_cs)
    out[71303169 + i] = val / cs;                          // new_embedding
}

extern "C" void kernel_launch(void* const* d_in, const int* in_sizes, int n_in,
                              void* d_out, int out_size, void* d_ws, size_t ws_size,
                              hipStream_t stream) {
    const float* x    = (const float*)d_in[0];   // [16,64,64,64]
    const float* E    = (const float*)d_in[1];   // [1024,64]
    const float* cs   = (const float*)d_in[2];   // [1024]
    const float* emaw = (const float*)d_in[3];   // [1024,64]
    float* out = (float*)d_out;
    float* ws  = (float*)d_ws;

    prep_kernel<<<256, 256, 0, stream>>>(E, ws);
    vq_main<<<512, 256, 0, stream>>>(x, E, out, ws);
    fin_cs<<<1, 1024, 0, stream>>>(cs, out, ws);
    fin_w<<<256, 256, 0, stream>>>(emaw, out, ws);
}